// Round 7
// baseline (235.275 us; speedup 1.0000x reference)
//
#include <hip/hip_runtime.h>

typedef __attribute__((ext_vector_type(8))) short short8;
typedef __attribute__((ext_vector_type(4))) float f32x4;

#define T_DIM 4096
#define C_DIM 128
#define U_DIM 256
#define BM 64
#define NR 68            // staged LDS rows: xbf rows t0 .. t0+67  (global t0-1 .. t0+66)
#define TP2 4098         // padded rows per batch in xbf: [zero, t=0..4095, zero]
#define NTB 2            // tiles per block (2-phase pipeline)

__device__ __forceinline__ unsigned short f2bf(float f) {
    unsigned int u = __float_as_uint(f);
    u += 0x7FFFu + ((u >> 16) & 1u);   // round-to-nearest-even
    return (unsigned short)(u >> 16);
}

// ---------------- kernel 1: f32->bf16 convert + per-row sumsq (16384) + wfrag (48) + scalars (1)
// xbf layout: per batch TP2 rows of 128 bf16 (256 B). Within a row, 16B chunks
// pre-swizzled: chunk c stored at c ^ ((t+1)&7) so main's LDS is linear-written
// (global_load_lds) and XOR-read conflict-free (rule #21: swizzle source+read, not dest).
__global__ __launch_bounds__(256) void prep_all(
        const float* __restrict__ inp, const float* __restrict__ w,
        const float* __restrict__ b, const float* __restrict__ p,
        const float* __restrict__ q,
        unsigned short* __restrict__ xbf, unsigned short* __restrict__ wfrag,
        float* __restrict__ ss, float* __restrict__ winv,
        float* __restrict__ p2, float* __restrict__ bc) {
    const int blk = blockIdx.x;
    const int tid = threadIdx.x;
    if (blk < 16384) {
        const int bb    = blk >> 9;            // 512 blocks per batch
        const int tbase = (blk & 511) * 8;     // 8 rows per block, no halo re-read
        const int gidx  = tid >> 5;            // 0..7
        const int hl    = tid & 31;
        const int t     = tbase + gidx;
        float4 v = *(const float4*)(inp + ((size_t)bb * T_DIM + t) * C_DIM + hl * 4);
        float part = v.x * v.x + v.y * v.y + v.z * v.z + v.w * v.w;
        #pragma unroll
        for (int o = 16; o > 0; o >>= 1) part += __shfl_xor(part, o, 32);
        if (hl == 0) ss[(size_t)bb * T_DIM + t] = part;
        int c  = hl >> 1;                      // 16B chunk index 0..15
        int cs = c ^ ((t + 1) & 7);            // swizzled position
        ushort4 sv;
        sv.x = f2bf(v.x); sv.y = f2bf(v.y); sv.z = f2bf(v.z); sv.w = f2bf(v.w);
        *(ushort4*)(xbf + ((size_t)bb * TP2 + t + 1) * 128 + cs * 8 + (hl & 1) * 4) = sv;
        if (tbase == 0 && tid < 32) {          // zero guard row t=-1
            ((ushort4*)(xbf + (size_t)bb * TP2 * 128))[tid] = make_ushort4(0, 0, 0, 0);
        }
        if (tbase == T_DIM - 8 && tid < 32) {  // zero guard row t=T
            ((ushort4*)(xbf + ((size_t)bb * TP2 + T_DIM + 1) * 128))[tid] = make_ushort4(0, 0, 0, 0);
        }
    } else if (blk < 16432) {
        int idx = (blk - 16384) * 256 + tid;   // 0..12287 lane-frags
        int ll = idx & 63;
        int nt = (idx >> 6) & 15;
        int ks = idx >> 10;                    // 0..11
        int n  = nt * 16 + (ll & 15);
        int k0 = ks * 32 + ((ll >> 4) << 3);
        #pragma unroll
        for (int j = 0; j < 8; ++j)
            wfrag[(size_t)idx * 8 + j] = f2bf(w[(k0 + j) * U_DIM + n]);
    } else {
        int u = tid;
        float sw = 0.f;
        for (int k = 0; k < 3 * C_DIM; ++k) {
            float v = w[k * U_DIM + u];
            sw += v * v;
        }
        float q2v = q[0] * q[0];
        winv[u] = 1.0f / (sqrtf(fmaxf(sw, 1e-12f)) + q2v);
        float pv = p[u];
        p2[u] = pv * pv;
        bc[u] = b[u];
    }
}

// ---------------- kernel 2: MFMA main, 2-tile 2-phase pipeline, global_load_lds staging.
__global__ __launch_bounds__(256, 4) void cossim_main(
        const unsigned short* __restrict__ xbf,
        const unsigned short* __restrict__ wfrag,
        const float* __restrict__ ss,
        const float* __restrict__ winv,
        const float* __restrict__ p2g,
        const float* __restrict__ bg,
        const float* __restrict__ qg,
        float* __restrict__ out) {
    __shared__ unsigned short xs[2][NR * 128];   // 2 x 17408 B, swizzled rows

    const int tid = threadIdx.x;
    const int bb  = blockIdx.x >> 5;             // batch
    const int tq  = blockIdx.x & 31;             // tile-pair index
    const int wid = tid >> 6;                    // wave id = u quarter
    const int l   = tid & 63;
    const int l15 = l & 15;
    const int lg  = l >> 4;

    const unsigned short* srcbase = xbf + (size_t)bb * TP2 * 128;
    const float* ssb = ss + (size_t)bb * T_DIM;
    const float q2 = qg[0] * qg[0];
    const short8* wf = (const short8*)wfrag;

    // ---- prologue: stage tile 0 into xs[0] ----
    {
        const unsigned short* src = srcbase + (size_t)(tq * NTB * BM) * 128;
        for (int j = wid; j < 17; j += 4) {
            __builtin_amdgcn_global_load_lds(
                (const __attribute__((address_space(1))) unsigned int*)(src + j * 512 + l * 8),
                (__attribute__((address_space(3))) unsigned int*)(&xs[0][j * 512]),
                16, 0, 0);
        }
    }
    __syncthreads();

    int cur = 0;
    for (int i = 0; i < NTB; ++i) {
        const int t0 = (tq * NTB + i) * BM;

        // ---- issue next tile's 17 global_load_lds into xs[cur^1] (zero VGPR state) ----
        if (i + 1 < NTB) {
            const unsigned short* src = srcbase + (size_t)(t0 + BM) * 128;
            for (int j = wid; j < 17; j += 4) {
                __builtin_amdgcn_global_load_lds(
                    (const __attribute__((address_space(1))) unsigned int*)(src + j * 512 + l * 8),
                    (__attribute__((address_space(3))) unsigned int*)(&xs[cur ^ 1][j * 512]),
                    16, 0, 0);
            }
        }

        // ---- MFMA on xs[cur]: each wave 64(t) x 64(u); A = w frag, B = x frag ----
        const unsigned short* xb = xs[cur];
        f32x4 acc[4][4];                         // [tf][uf]
        #pragma unroll
        for (int tf = 0; tf < 4; ++tf)
            #pragma unroll
            for (int uf = 0; uf < 4; ++uf)
                acc[tf][uf] = (f32x4){0.f, 0.f, 0.f, 0.f};

        #pragma unroll
        for (int ks = 0; ks < 12; ++ks) {
            const int tap = ks >> 2;
            const int cb  = (ks & 3) * 4;        // base 16B-chunk within row
            short8 xv[4], wvv[4];
            #pragma unroll
            for (int tf = 0; tf < 4; ++tf) {
                int r  = tf * 16 + l15 + tap;    // LDS row (= t - t0 + 1)
                int ch = (cb + lg) ^ (r & 7);    // un-swizzle
                xv[tf] = *(const short8*)(xb + r * 128 + ch * 8);
            }
            #pragma unroll
            for (int uf = 0; uf < 4; ++uf)
                wvv[uf] = wf[(size_t)(ks * 16 + wid * 4 + uf) * 64 + l];
            #pragma unroll
            for (int tf = 0; tf < 4; ++tf)
                #pragma unroll
                for (int uf = 0; uf < 4; ++uf)
                    acc[tf][uf] = __builtin_amdgcn_mfma_f32_16x16x32_bf16(
                        wvv[uf], xv[tf], acc[tf][uf], 0, 0, 0);
        }

        // ---- epilogue: xninv inline from ss (L2-hot); dwordx4 stores ----
        #pragma unroll
        for (int tf = 0; tf < 4; ++tf) {
            int trow = tf * 16 + l15;
            int t    = t0 + trow;
            float s0 = ssb[t];
            float sm = (t > 0)         ? ssb[t - 1] : 0.f;
            float sp = (t < T_DIM - 1) ? ssb[t + 1] : 0.f;
            float xi = 1.0f / (sqrtf(fmaxf(s0 + sm + sp, 1e-12f)) + q2);
            float* orow = out + ((size_t)bb * T_DIM + t) * U_DIM;
            #pragma unroll
            for (int uf = 0; uf < 4; ++uf) {
                int uc = wid * 64 + uf * 16 + lg * 4;
                f32x4 wiv = *(const f32x4*)(winv + uc);
                f32x4 ppv = *(const f32x4*)(p2g + uc);
                f32x4 bbv = *(const f32x4*)(bg + uc);
                f32x4 r;
                #pragma unroll
                for (int j = 0; j < 4; ++j) {
                    float raw = acc[tf][uf][j];
                    float y   = raw * xi * wiv[j];
                    float ay  = fabsf(y) + 1e-12f;
                    float pw  = ppv[j];
                    float rr  = ay;
                    if (pw != 1.0f) rr = powf(ay, pw);   // p==1 at runtime: skipped
                    float s   = (raw > 0.f) ? 1.f : ((raw < 0.f) ? -1.f : 0.f);
                    r[j] = s * rr + bbv[j];
                }
                *(f32x4*)(orow + uc) = r;
            }
        }

        __syncthreads();   // drains vmcnt: tile i+1's LDS writes complete & visible
        cur ^= 1;
    }
}

extern "C" void kernel_launch(void* const* d_in, const int* in_sizes, int n_in,
                              void* d_out, int out_size, void* d_ws, size_t ws_size,
                              hipStream_t stream) {
    const float* inp = (const float*)d_in[0];
    const float* w   = (const float*)d_in[1];
    const float* b   = (const float*)d_in[2];
    const float* p   = (const float*)d_in[3];
    const float* q   = (const float*)d_in[4];
    float* out = (float*)d_out;

    // ws layout
    unsigned short* xbf   = (unsigned short*)d_ws;                       // 32*4098*256 B = 33,570,816
    unsigned short* wfrag = (unsigned short*)((char*)d_ws + 33570816);   // 196,608 B
    float* ssb  = (float*)((char*)d_ws + 33570816 + 196608);             // 32*4096*4 = 524,288 B
    float* winv = ssb + 32 * 4096;
    float* p2   = winv + 256;
    float* bc   = p2 + 256;

    prep_all<<<16433, 256, 0, stream>>>(inp, w, b, p, q, xbf, wfrag, ssb, winv, p2, bc);
    cossim_main<<<1024, 256, 0, stream>>>(xbf, wfrag, ssb, winv, p2, bc, q, out);
}

// Round 8
// 127.858 us; speedup vs baseline: 1.8401x; 1.8401x over previous
//
#include <hip/hip_runtime.h>

typedef __attribute__((ext_vector_type(8))) short short8;
typedef __attribute__((ext_vector_type(4))) float f32x4;

#define T_DIM 4096
#define C_DIM 128
#define U_DIM 256
#define BM 64
#define TP2 4098         // padded rows per batch in xbf: [zero, t=0..4095, zero]

__device__ __forceinline__ unsigned short f2bf(float f) {
    unsigned int u = __float_as_uint(f);
    u += 0x7FFFu + ((u >> 16) & 1u);   // round-to-nearest-even
    return (unsigned short)(u >> 16);
}

// ---------------- kernel 1: f32->bf16 convert (linear layout) + xninv (16384 blocks)
//                  + wfrag pack (48) + scalars (1)
__global__ __launch_bounds__(320) void prep_all(
        const float* __restrict__ inp, const float* __restrict__ w,
        const float* __restrict__ b, const float* __restrict__ p,
        const float* __restrict__ q,
        unsigned short* __restrict__ xbf, unsigned short* __restrict__ wfrag,
        float* __restrict__ xninv, float* __restrict__ winv,
        float* __restrict__ p2, float* __restrict__ bc) {
    const int blk = blockIdx.x;
    const int tid = threadIdx.x;
    if (blk < 16384) {
        __shared__ float ss_s[10];
        const int bb    = blk >> 9;            // 512 blocks per batch
        const int tbase = (blk & 511) * 8;     // 8 owned rows per block
        const int gidx  = tid >> 5;            // 0..9 -> rows tbase-1 .. tbase+8
        const int hl    = tid & 31;
        const int t     = tbase - 1 + gidx;
        float4 v = make_float4(0.f, 0.f, 0.f, 0.f);
        if ((unsigned)t < T_DIM)
            v = *(const float4*)(inp + ((size_t)bb * T_DIM + t) * C_DIM + hl * 4);
        float part = v.x * v.x + v.y * v.y + v.z * v.z + v.w * v.w;
        #pragma unroll
        for (int o = 16; o > 0; o >>= 1) part += __shfl_xor(part, o, 32);
        if (hl == 0) ss_s[gidx] = part;
        // write owned rows only (gidx 1..8), linear bf16 layout at xbf row t+1
        if (gidx >= 1 && gidx <= 8) {
            ushort4 sv;
            sv.x = f2bf(v.x); sv.y = f2bf(v.y); sv.z = f2bf(v.z); sv.w = f2bf(v.w);
            *(ushort4*)(xbf + ((size_t)bb * TP2 + t + 1) * 128 + hl * 4) = sv;
        }
        if (tbase == 0 && tid < 32)            // zero guard row (t = -1)
            ((ushort4*)(xbf + (size_t)bb * TP2 * 128))[tid] = make_ushort4(0, 0, 0, 0);
        if (tbase == T_DIM - 8 && tid < 32)    // zero guard row (t = T)
            ((ushort4*)(xbf + ((size_t)bb * TP2 + T_DIM + 1) * 128))[tid] = make_ushort4(0, 0, 0, 0);
        __syncthreads();
        if (tid < 8) {
            float q2v = q[0] * q[0];
            float s3  = ss_s[tid] + ss_s[tid + 1] + ss_s[tid + 2];
            xninv[(size_t)bb * T_DIM + tbase + tid] =
                1.0f / (sqrtf(fmaxf(s3, 1e-12f)) + q2v);
        }
    } else if (blk < 16432) {
        if (tid < 256) {
            int idx = (blk - 16384) * 256 + tid;    // 0..12287 lane-frags
            int ll = idx & 63;
            int nt = (idx >> 6) & 15;
            int ks = idx >> 10;                     // 0..11
            int n  = nt * 16 + (ll & 15);
            int k0 = ks * 32 + ((ll >> 4) << 3);
            #pragma unroll
            for (int j = 0; j < 8; ++j)
                wfrag[(size_t)idx * 8 + j] = f2bf(w[(k0 + j) * U_DIM + n]);
        }
    } else {
        if (tid < 256) {
            int u = tid;
            float sw = 0.f;
            for (int k = 0; k < 3 * C_DIM; ++k) {
                float v = w[k * U_DIM + u];
                sw += v * v;
            }
            float q2v = q[0] * q[0];
            winv[u] = 1.0f / (sqrtf(fmaxf(sw, 1e-12f)) + q2v);
            float pv = p[u];
            p2[u] = pv * pv;
            bc[u] = b[u];
        }
    }
}

// ---------------- kernel 2: barrier-free, LDS-free MFMA main.
// Each wave: 64(t) x 64(u). x fragments loaded directly from L2-resident bf16 xbf.
__global__ __launch_bounds__(256, 3) void cossim_main(
        const unsigned short* __restrict__ xbf,
        const unsigned short* __restrict__ wfrag,
        const float* __restrict__ xninv,
        const float* __restrict__ winv,
        const float* __restrict__ p2g,
        const float* __restrict__ bg,
        float* __restrict__ out) {
    const int tid = threadIdx.x;
    const int bb  = blockIdx.x >> 6;           // batch
    const int t0  = (blockIdx.x & 63) * BM;    // tile start
    const int wid = tid >> 6;                  // wave id = u quarter
    const int l   = tid & 63;
    const int l15 = l & 15;
    const int lg  = l >> 4;

    // xbf row (tf*16 + l15 + tap) relative to this base == global t row t0+tf*16+l15+(tap-1)
    const unsigned short* xrow = xbf + ((size_t)bb * TP2 + t0) * 128;
    const short8* wf = (const short8*)wfrag;

    f32x4 acc[4][4];                           // [tf][uf]
    #pragma unroll
    for (int tf = 0; tf < 4; ++tf)
        #pragma unroll
        for (int uf = 0; uf < 4; ++uf)
            acc[tf][uf] = (f32x4){0.f, 0.f, 0.f, 0.f};

    #pragma unroll
    for (int ks = 0; ks < 12; ++ks) {
        const int tap = ks >> 2;
        const int c0  = (ks & 3) * 32 + lg * 8;
        short8 xv[4], wvv[4];
        #pragma unroll
        for (int tf = 0; tf < 4; ++tf)
            xv[tf] = *(const short8*)(xrow + (size_t)(tf * 16 + l15 + tap) * 128 + c0);
        #pragma unroll
        for (int uf = 0; uf < 4; ++uf)
            wvv[uf] = wf[(size_t)(ks * 16 + wid * 4 + uf) * 64 + l];
        #pragma unroll
        for (int tf = 0; tf < 4; ++tf)
            #pragma unroll
            for (int uf = 0; uf < 4; ++uf)
                acc[tf][uf] = __builtin_amdgcn_mfma_f32_16x16x32_bf16(
                    wvv[uf], xv[tf], acc[tf][uf], 0, 0, 0);
    }

    // ---- epilogue: lane holds 4 consecutive u at fixed t -> dwordx4 stores ----
    #pragma unroll
    for (int tf = 0; tf < 4; ++tf) {
        int t = t0 + tf * 16 + l15;
        float xi = xninv[(size_t)bb * T_DIM + t];
        float* orow = out + ((size_t)bb * T_DIM + t) * U_DIM;
        #pragma unroll
        for (int uf = 0; uf < 4; ++uf) {
            int uc = wid * 64 + uf * 16 + lg * 4;
            f32x4 wiv = *(const f32x4*)(winv + uc);
            f32x4 ppv = *(const f32x4*)(p2g + uc);
            f32x4 bbv = *(const f32x4*)(bg + uc);
            f32x4 r;
            #pragma unroll
            for (int j = 0; j < 4; ++j) {
                float raw = acc[tf][uf][j];
                float y   = raw * xi * wiv[j];
                float ay  = fabsf(y) + 1e-12f;
                float pw  = ppv[j];
                float rr  = ay;
                if (pw != 1.0f) rr = powf(ay, pw);   // p==1 at runtime: skipped
                float s   = (raw > 0.f) ? 1.f : ((raw < 0.f) ? -1.f : 0.f);
                r[j] = s * rr + bbv[j];
            }
            *(f32x4*)(orow + uc) = r;
        }
    }
}

extern "C" void kernel_launch(void* const* d_in, const int* in_sizes, int n_in,
                              void* d_out, int out_size, void* d_ws, size_t ws_size,
                              hipStream_t stream) {
    const float* inp = (const float*)d_in[0];
    const float* w   = (const float*)d_in[1];
    const float* b   = (const float*)d_in[2];
    const float* p   = (const float*)d_in[3];
    const float* q   = (const float*)d_in[4];
    float* out = (float*)d_out;

    // ws layout
    unsigned short* xbf   = (unsigned short*)d_ws;                       // 32*4098*256 B = 33,570,816
    unsigned short* wfrag = (unsigned short*)((char*)d_ws + 33570816);   // 196,608 B
    float* xninv = (float*)((char*)d_ws + 33570816 + 196608);            // 524,288 B
    float* winv  = xninv + 32 * 4096;
    float* p2    = winv + 256;
    float* bc    = p2 + 256;

    prep_all<<<16433, 320, 0, stream>>>(inp, w, b, p, q, xbf, wfrag, xninv, winv, p2, bc);
    cossim_main<<<2048, 256, 0, stream>>>(xbf, wfrag, xninv, winv, p2, bc, out);
}

// Round 9
// 96.899 us; speedup vs baseline: 2.4280x; 1.3195x over previous
//
#include <hip/hip_runtime.h>

typedef __attribute__((ext_vector_type(8))) short short8;
typedef __attribute__((ext_vector_type(4))) float f32x4;

#define T_DIM 4096
#define C_DIM 128
#define U_DIM 256
#define BM 32
#define NRW 34     // BM + 2 halo rows
#define LDK 136    // padded LDS row stride (bf16): 272B -> 2-way bank alias (free)

__device__ __forceinline__ unsigned short f2bf(float f) {
    unsigned int u = __float_as_uint(f);
    u += 0x7FFFu + ((u >> 16) & 1u);   // round-to-nearest-even
    return (unsigned short)(u >> 16);
}

// Pre-pack w into MFMA fragment order: wfrag[ks][nt][lane][8] bf16,
// where k = ks*32 + (lane>>4)*8 + j, u = nt*16 + (lane&15).
__global__ void prep_kernel(const float* __restrict__ w,
                            const float* __restrict__ b,
                            const float* __restrict__ p,
                            const float* __restrict__ q,
                            unsigned short* __restrict__ wfrag,
                            float* __restrict__ winv,
                            float* __restrict__ p2,
                            float* __restrict__ bc) {
    if (blockIdx.x < 48) {
        int idx = blockIdx.x * 256 + threadIdx.x;   // 0..12287 lane-frags
        int l  = idx & 63;
        int nt = (idx >> 6) & 15;
        int ks = idx >> 10;                         // 0..11
        int n  = nt * 16 + (l & 15);
        int k0 = ks * 32 + ((l >> 4) << 3);
        #pragma unroll
        for (int j = 0; j < 8; ++j) {
            wfrag[(size_t)idx * 8 + j] = f2bf(w[(k0 + j) * U_DIM + n]);
        }
    } else {
        int u = threadIdx.x;                        // 0..255
        float ss = 0.f;
        for (int k = 0; k < 3 * C_DIM; ++k) {
            float v = w[k * U_DIM + u];
            ss += v * v;
        }
        float q2 = q[0] * q[0];
        winv[u] = 1.0f / (sqrtf(fmaxf(ss, 1e-12f)) + q2);
        float pv = p[u];
        p2[u] = pv * pv;
        bc[u] = b[u];
    }
}

// Single-wave workgroups: each block = 1 wave computing 32(t) x 64(u).
// No cross-wave barriers anywhere -> resident waves free-run at random phases.
__global__ __launch_bounds__(64, 4) void cossim_main(
        const float* __restrict__ inp,
        const unsigned short* __restrict__ wfrag,
        const float* __restrict__ winv,
        const float* __restrict__ p2g,
        const float* __restrict__ bg,
        const float* __restrict__ qg,
        float* __restrict__ out) {
    __shared__ unsigned short xs[NRW][LDK];   // 9.2 KB
    __shared__ float ss_s[NRW];
    __shared__ float xninv_s[BM];

    const int tid = threadIdx.x;              // 0..63

    // XCD-bijective swizzle (16384 % 8 == 0): each XCD gets a contiguous
    // 2048-work chunk so the 4 uq-siblings of a t-tile share one L2.
    int bid = blockIdx.x;
    bid = (bid & 7) * 2048 + (bid >> 3);
    const int bb = bid >> 9;                  // batch (512 work ids per batch)
    const int tt = (bid >> 2) & 127;          // t-tile within batch
    const int uq = bid & 3;                   // u 64-col quarter
    const int t0 = tt * BM;

    const float q2 = qg[0] * qg[0];

    // ---- stage 34 rows (t0-1 .. t0+32) f32 -> bf16 LDS; f32 sumsq per row ----
    {
        const int half = tid >> 5;            // 0..1 (row within pair)
        const int lc   = (tid & 31) * 4;      // f32 column
        for (int rr = 0; rr < 17; ++rr) {
            int r = rr * 2 + half;
            int t = t0 + r - 1;
            float4 v = make_float4(0.f, 0.f, 0.f, 0.f);
            if ((unsigned)t < T_DIM)
                v = *(const float4*)(inp + ((size_t)bb * T_DIM + t) * C_DIM + lc);
            float part = v.x * v.x + v.y * v.y + v.z * v.z + v.w * v.w;
            #pragma unroll
            for (int o = 16; o > 0; o >>= 1) part += __shfl_xor(part, o, 32);
            if ((tid & 31) == 0) ss_s[r] = part;
            ushort4 sv;
            sv.x = f2bf(v.x); sv.y = f2bf(v.y);
            sv.z = f2bf(v.z); sv.w = f2bf(v.w);
            *(ushort4*)(&xs[r][lc]) = sv;
        }
    }
    __syncthreads();                          // 1-wave block: just a waitcnt
    if (tid < BM) {
        float s3 = ss_s[tid] + ss_s[tid + 1] + ss_s[tid + 2];
        xninv_s[tid] = 1.0f / (sqrtf(fmaxf(s3, 1e-12f)) + q2);
    }
    __syncthreads();

    // ---- MFMA: wave = 32(t) x 64(u); A = w frag (m->u), B = x frag (n->t) ----
    const int l15 = tid & 15;
    const int lg  = tid >> 4;                 // 0..3

    f32x4 acc[2][4];                          // [tf][uf] -> only 32 AGPRs
    #pragma unroll
    for (int tf = 0; tf < 2; ++tf)
        #pragma unroll
        for (int uf = 0; uf < 4; ++uf)
            acc[tf][uf] = (f32x4){0.f, 0.f, 0.f, 0.f};

    const short8* wf = (const short8*)wfrag;

    #pragma unroll
    for (int ks = 0; ks < 12; ++ks) {
        const int tap = ks >> 2;                    // tap 0..2
        const int c0  = (ks & 3) * 32 + lg * 8;     // bf16 column within tap
        short8 xv[2], wv[4];
        #pragma unroll
        for (int tf = 0; tf < 2; ++tf) {
            int row = tf * 16 + l15 + tap;          // halo-shifted LDS row
            xv[tf] = *(const short8*)(&xs[row][c0]);
        }
        #pragma unroll
        for (int uf = 0; uf < 4; ++uf)
            wv[uf] = wf[(size_t)(ks * 16 + uq * 4 + uf) * 64 + tid];
        #pragma unroll
        for (int tf = 0; tf < 2; ++tf)
            #pragma unroll
            for (int uf = 0; uf < 4; ++uf)
                acc[tf][uf] = __builtin_amdgcn_mfma_f32_16x16x32_bf16(
                    wv[uf], xv[tf], acc[tf][uf], 0, 0, 0);
    }

    // ---- epilogue: lane holds 4 consecutive u at fixed t -> dwordx4 stores ----
    #pragma unroll
    for (int tf = 0; tf < 2; ++tf) {
        int trow = tf * 16 + l15;
        float xi = xninv_s[trow];
        float* orow = out + ((size_t)bb * T_DIM + t0 + trow) * U_DIM;
        #pragma unroll
        for (int uf = 0; uf < 4; ++uf) {
            int uc = uq * 64 + uf * 16 + lg * 4;
            f32x4 wiv = *(const f32x4*)(winv + uc);
            f32x4 ppv = *(const f32x4*)(p2g + uc);
            f32x4 bbv = *(const f32x4*)(bg + uc);
            f32x4 r;
            #pragma unroll
            for (int j = 0; j < 4; ++j) {
                float raw = acc[tf][uf][j];
                float y   = raw * xi * wiv[j];
                float ay  = fabsf(y) + 1e-12f;
                float pw  = ppv[j];
                float rr  = ay;
                if (pw != 1.0f) rr = powf(ay, pw);   // p==1 at runtime: skipped
                float s   = (raw > 0.f) ? 1.f : ((raw < 0.f) ? -1.f : 0.f);
                r[j] = s * rr + bbv[j];
            }
            *(f32x4*)(orow + uc) = r;
        }
    }
}

extern "C" void kernel_launch(void* const* d_in, const int* in_sizes, int n_in,
                              void* d_out, int out_size, void* d_ws, size_t ws_size,
                              hipStream_t stream) {
    const float* inp = (const float*)d_in[0];
    const float* w   = (const float*)d_in[1];
    const float* b   = (const float*)d_in[2];
    const float* p   = (const float*)d_in[3];
    const float* q   = (const float*)d_in[4];
    float* out = (float*)d_out;

    unsigned short* wfrag = (unsigned short*)d_ws;            // 196608 B
    float* winv = (float*)((char*)d_ws + 196608);
    float* p2   = winv + 256;
    float* bc   = p2 + 256;

    prep_kernel<<<49, 256, 0, stream>>>(w, b, p, q, wfrag, winv, p2, bc);
    cossim_main<<<16384, 64, 0, stream>>>(inp, wfrag, winv, p2, bc, q, out);
}

// Round 10
// 73.756 us; speedup vs baseline: 3.1899x; 1.3138x over previous
//
#include <hip/hip_runtime.h>

typedef __attribute__((ext_vector_type(8))) short short8;
typedef __attribute__((ext_vector_type(4))) float f32x4;

#define T_DIM 4096
#define C_DIM 128
#define U_DIM 256
#define BM 128
#define NROWS 130   // BM + 2 halo rows
#define LDK 136     // padded LDS row stride (bf16 elems)

__device__ __forceinline__ unsigned short f2bf(float f) {
    unsigned int u = __float_as_uint(f);
    u += 0x7FFFu + ((u >> 16) & 1u);   // round-to-nearest-even
    return (unsigned short)(u >> 16);
}

// Pre-pack w into MFMA fragment order: wfrag[ks][nt][lane][8] bf16,
// where k = ks*32 + (lane>>4)*8 + j, u = nt*16 + (lane&15).
__global__ void prep_kernel(const float* __restrict__ w,
                            const float* __restrict__ b,
                            const float* __restrict__ p,
                            const float* __restrict__ q,
                            unsigned short* __restrict__ wfrag,
                            float* __restrict__ winv,
                            float* __restrict__ p2,
                            float* __restrict__ bc) {
    if (blockIdx.x < 48) {
        int idx = blockIdx.x * 256 + threadIdx.x;   // 0..12287 lane-frags
        int l  = idx & 63;
        int nt = (idx >> 6) & 15;
        int ks = idx >> 10;                         // 0..11
        int n  = nt * 16 + (l & 15);
        int k0 = ks * 32 + ((l >> 4) << 3);
        #pragma unroll
        for (int j = 0; j < 8; ++j) {
            wfrag[(size_t)idx * 8 + j] = f2bf(w[(k0 + j) * U_DIM + n]);
        }
    } else {
        int u = threadIdx.x;                        // 0..255
        float ss = 0.f;
        for (int k = 0; k < 3 * C_DIM; ++k) {
            float v = w[k * U_DIM + u];
            ss += v * v;
        }
        float q2 = q[0] * q[0];
        winv[u] = 1.0f / (sqrtf(fmaxf(ss, 1e-12f)) + q2);
        float pv = p[u];
        p2[u] = pv * pv;
        bc[u] = b[u];
    }
}

__global__ __launch_bounds__(512, 4) void cossim_main(
        const float* __restrict__ inp,
        const unsigned short* __restrict__ wfrag,
        const float* __restrict__ winv,
        const float* __restrict__ p2g,
        const float* __restrict__ bg,
        const float* __restrict__ qg,
        float* __restrict__ out) {
    __shared__ unsigned short inp_s[NROWS][LDK];
    __shared__ float ss_s[NROWS];
    __shared__ float xninv_s[BM];

    const int tid  = threadIdx.x;
    const int bidx = blockIdx.x;
    const int bb   = bidx >> 5;          // batch index (32 tiles per batch)
    const int t0   = (bidx & 31) * BM;   // tile start within batch

    // ---- Stage 130 input rows (t0-1 .. t0+128) as bf16; f32 sumsq per row ----
    {
        const int r0 = tid >> 5;         // 0..15
        const int lc = (tid & 31) * 4;   // float column
        float4 v[9];
        #pragma unroll
        for (int i = 0; i < 9; ++i) {
            int r = r0 + i * 16;
            int t = t0 + r - 1;
            float4 val = make_float4(0.f, 0.f, 0.f, 0.f);
            if (r < NROWS && t >= 0 && t < T_DIM) {
                val = *(const float4*)(inp + ((size_t)bb * T_DIM + t) * C_DIM + lc);
            }
            v[i] = val;
        }
        #pragma unroll
        for (int i = 0; i < 9; ++i) {
            int r = r0 + i * 16;
            if (r < NROWS) {
                float4 val = v[i];
                float part = val.x * val.x + val.y * val.y + val.z * val.z + val.w * val.w;
                #pragma unroll
                for (int o = 16; o > 0; o >>= 1) part += __shfl_xor(part, o, 32);
                if ((tid & 31) == 0) ss_s[r] = part;
                ushort4 sv;
                sv.x = f2bf(val.x); sv.y = f2bf(val.y);
                sv.z = f2bf(val.z); sv.w = f2bf(val.w);
                *(ushort4*)(&inp_s[r][lc]) = sv;
            }
        }
    }
    __syncthreads();
    if (tid < BM) {
        float s3 = ss_s[tid] + ss_s[tid + 1] + ss_s[tid + 2];
        float q2 = qg[0] * qg[0];
        xninv_s[tid] = 1.0f / (sqrtf(fmaxf(s3, 1e-12f)) + q2);
    }
    __syncthreads();

    // ---- MFMA: 8 waves as 2(T) x 4(U); each wave 64(t) x 64(u) ----
    // A = w fragment (m -> u), B = x fragment (n -> t).
    // D[u][t]: C/D layout col = lane&15 -> t, row = (lane>>4)*4 + j -> u.
    const int wid = tid >> 6;
    const int l   = tid & 63;
    const int tw  = wid >> 2;        // 0..1 (t 64-row half)
    const int uw  = wid & 3;         // 0..3 (u 64-col quarter)
    const int l15 = l & 15;
    const int lg  = l >> 4;          // 0..3

    f32x4 acc[4][4];                 // [tf][uf]
    #pragma unroll
    for (int tf = 0; tf < 4; ++tf)
        #pragma unroll
        for (int uf = 0; uf < 4; ++uf)
            acc[tf][uf] = (f32x4){0.f, 0.f, 0.f, 0.f};

    const short8* wf = (const short8*)wfrag;

    #pragma unroll
    for (int ks = 0; ks < 12; ++ks) {
        const int tap = ks >> 2;                    // which of the 3 taps
        const int c0  = (ks & 3) * 32 + lg * 8;     // bf16 column within tap
        short8 xv[4], wv[4];
        #pragma unroll
        for (int tf = 0; tf < 4; ++tf) {
            int row = tw * 64 + tf * 16 + l15 + tap;   // halo-shifted LDS row
            xv[tf] = *(const short8*)(&inp_s[row][c0]);
        }
        #pragma unroll
        for (int uf = 0; uf < 4; ++uf) {
            wv[uf] = wf[(size_t)(ks * 16 + uw * 4 + uf) * 64 + l];
        }
        #pragma unroll
        for (int tf = 0; tf < 4; ++tf)
            #pragma unroll
            for (int uf = 0; uf < 4; ++uf)
                acc[tf][uf] = __builtin_amdgcn_mfma_f32_16x16x32_bf16(
                    wv[uf], xv[tf], acc[tf][uf], 0, 0, 0);
    }

    // ---- Epilogue: compact — no libm powf (code-size / I$ fix).
    // rr = (pw==1) ? ay : 2^(pw*log2(ay));  sign applied via copysign.
    #pragma unroll
    for (int tf = 0; tf < 4; ++tf) {
        int trow = tw * 64 + tf * 16 + l15;
        float xi = xninv_s[trow];
        float* orow = out + ((size_t)bb * T_DIM + t0 + trow) * U_DIM;
        #pragma unroll
        for (int uf = 0; uf < 4; ++uf) {
            int uc = uw * 64 + uf * 16 + lg * 4;
            f32x4 wiv = *(const f32x4*)(winv + uc);
            f32x4 ppv = *(const f32x4*)(p2g + uc);
            f32x4 bbv = *(const f32x4*)(bg + uc);
            f32x4 r;
            #pragma unroll
            for (int j = 0; j < 4; ++j) {
                float raw = acc[tf][uf][j];
                float y   = raw * xi * wiv[j];
                float ay  = fabsf(y) + 1e-12f;
                float pw  = ppv[j];
                float rr  = (pw == 1.0f) ? ay : exp2f(pw * __log2f(ay));
                r[j] = __builtin_copysignf(rr, raw) + bbv[j];
            }
            *(f32x4*)(orow + uc) = r;
        }
    }
}

extern "C" void kernel_launch(void* const* d_in, const int* in_sizes, int n_in,
                              void* d_out, int out_size, void* d_ws, size_t ws_size,
                              hipStream_t stream) {
    const float* inp = (const float*)d_in[0];
    const float* w   = (const float*)d_in[1];
    const float* b   = (const float*)d_in[2];
    const float* p   = (const float*)d_in[3];
    const float* q   = (const float*)d_in[4];
    float* out = (float*)d_out;

    unsigned short* wfrag = (unsigned short*)d_ws;            // 12*16*64*8 bf16 = 196608 B
    float* winv = (float*)((char*)d_ws + 196608);
    float* p2   = winv + 256;
    float* bc   = p2 + 256;

    prep_kernel<<<49, 256, 0, stream>>>(w, b, p, q, wfrag, winv, p2, bc);
    cossim_main<<<1024, 512, 0, stream>>>(inp, wfrag, winv, p2, bc, q, out);
}